// Round 13
// baseline (233.098 us; speedup 1.0000x reference)
//
#include <hip/hip_runtime.h>
#include <hip/hip_bf16.h>

// B=32, T=1024, D=256 fixed by the reference problem.
typedef __attribute__((ext_vector_type(8))) short bf16x8;
typedef __attribute__((ext_vector_type(4))) float f32x4;

#define INVT (1.0f/0.07f)

static __device__ __forceinline__ short f2bf(float f){
    unsigned int u = __float_as_uint(f);
    unsigned int r = (u + 0x7fffu + ((u >> 16) & 1u)) >> 16;
    return (short)r;
}
static __device__ __forceinline__ float bf2f(short s){
    return __uint_as_float(((unsigned int)(unsigned short)s) << 16);
}

// async global->LDS, 16B per lane; LDS dest = wave-uniform base + lane*16
static __device__ __forceinline__ void gld16(const void* g, void* l){
    __builtin_amdgcn_global_load_lds(
        (const __attribute__((address_space(1))) unsigned int*)g,
        (__attribute__((address_space(3))) unsigned int*)l, 16, 0, 0);
}

// ---- prep: blocks 0..511 convert W to bf16; blocks 512..543 per-batch rank scan + zero bsum
__global__ __launch_bounds__(256) void prep_kernel(const float* __restrict__ Weeg,
                                                   const float* __restrict__ Weye,
                                                   const int* __restrict__ mask,
                                                   short* __restrict__ Wout,
                                                   int* __restrict__ rank,
                                                   int* __restrict__ idx,
                                                   int* __restrict__ Tv,
                                                   float* __restrict__ cb,
                                                   float* __restrict__ bsum){
    __shared__ int ssum[256];
    int tid = threadIdx.x;
    if (blockIdx.x < 512){
        int i = blockIdx.x * 256 + tid;
        float v = (i < 65536) ? Weeg[i] : Weye[i - 65536];
        Wout[i] = f2bf(v);
        return;
    }
    int b = blockIdx.x - 512;
    if (tid == 0) bsum[b] = 0.f;
    int local[4]; int s = 0;
    #pragma unroll
    for (int q = 0; q < 4; ++q){
        int t = tid*4 + q;
        local[q] = (mask[b*1024 + t] > 0) ? 1 : 0;
        s += local[q];
    }
    ssum[tid] = s;
    __syncthreads();
    for (int off = 1; off < 256; off <<= 1){
        int add = (tid >= off) ? ssum[tid - off] : 0;
        __syncthreads();
        ssum[tid] += add;
        __syncthreads();
    }
    int run = ssum[tid] - s;
    #pragma unroll
    for (int q = 0; q < 4; ++q){
        int t = tid*4 + q;
        int g = b*1024 + t;
        run += local[q];
        rank[g] = run - 1;
        cb[g]   = local[q] ? 0.0f : -1e9f;
        if (local[q]) idx[b*1024 + run - 1] = t;
    }
    if (tid == 255) Tv[b] = ssum[255];
}

// ---- fused projection + L2 normalize, both modalities (blockIdx.y selects).
// 2 x 16KB double-buffered W staging, 8 chunks of 32 W-rows, issue-ahead
// pipeline (drains overlapped). 32 KB LDS -> 4 blocks/CU. Dense epilogue via
// XOR-swizzled per-wave LDS transpose bounce -> coalesced 16B/lane stores.
__global__ __launch_bounds__(256, 4) void proj_kernel(const float* __restrict__ Aeeg,
                                                      const float* __restrict__ Aeye,
                                                      const short* __restrict__ Wbf,
                                                      short* __restrict__ Eout,
                                                      short* __restrict__ Vout){
    __shared__ short sW[2][32 * 256];   // 2 x 16KB, XOR-swizzled in 16B blocks
    int sel = blockIdx.y;
    const float* A   = sel ? Aeye : Aeeg;
    const short* W   = Wbf + sel * 65536;
    short*       Out = sel ? Vout : Eout;

    int tid = threadIdx.x;
    int w = tid >> 6, lane = tid & 63;
    int l15 = lane & 15, lq = lane >> 4;
    int kb  = lq * 8;
    int row0 = blockIdx.x * 64;

    int ro   = lane >> 5;        // 0..1: row within a 1KB gld16 issue
    int cs   = lane & 31;        // 16B col-block within a 512B row
    int s7   = l15 & 7;

    // stage chunk ck (32 W-rows) into buf: wave w covers rows [w*8, +8), 4 issues
    #define PROJ_STAGE(ck, buf)                                              \
        _Pragma("unroll")                                                    \
        for (int p = 0; p < 4; ++p){                                         \
            int rr = (p*2 + ro) & 7;                                         \
            gld16(W + (size_t)((ck)*32 + w*8 + p*2 + ro)*256 + (cs ^ rr)*8,  \
                  &sW[buf][(w*8 + p*2) * 256]);                              \
        }

    PROJ_STAGE(0, 0)
    PROJ_STAGE(1, 1)

    // X-row fragments (B-operand), f32 -> bf16 (HBM; drains with chunk0/1)
    bf16x8 xf[8];
    {
        const float* ap = A + (size_t)(row0 + w*16 + l15) * 256 + kb;
        #pragma unroll
        for (int g = 0; g < 8; ++g){
            float4 x0 = *(const float4*)(ap + g*32);
            float4 x1 = *(const float4*)(ap + g*32 + 4);
            bf16x8 t;
            t[0]=f2bf(x0.x); t[1]=f2bf(x0.y); t[2]=f2bf(x0.z); t[3]=f2bf(x0.w);
            t[4]=f2bf(x1.x); t[5]=f2bf(x1.y); t[6]=f2bf(x1.z); t[7]=f2bf(x1.w);
            xf[g] = t;
        }
    }

    f32x4 acc[16];
    #pragma unroll
    for (int q = 0; q < 16; ++q) acc[q] = (f32x4){0.f,0.f,0.f,0.f};

    __syncthreads();   // c0, c1, xf ready

    // compute chunk 0 (e-tiles 0..1) from buf0
    #pragma unroll
    for (int nt = 0; nt < 2; ++nt){
        f32x4 c = acc[nt];
        int rbase = (nt*16 + l15) * 256;
        #pragma unroll
        for (int g = 0; g < 8; ++g){
            bf16x8 wf = *(const bf16x8*)&sW[0][rbase + (((g*4 + lq) ^ s7) << 3)];
            c = __builtin_amdgcn_mfma_f32_16x16x32_bf16(wf, xf[g], c, 0, 0, 0);
        }
        acc[nt] = c;
    }

    // chunks 1..7: sync; issue k+1; compute k
    #pragma unroll
    for (int k = 1; k < 8; ++k){
        __syncthreads();
        if (k < 7){ PROJ_STAGE(k+1, (k+1)&1) }
        #pragma unroll
        for (int nt = 0; nt < 2; ++nt){
            f32x4 c = acc[k*2 + nt];
            int rbase = (nt*16 + l15) * 256;
            #pragma unroll
            for (int g = 0; g < 8; ++g){
                bf16x8 wf = *(const bf16x8*)&sW[k&1][rbase + (((g*4 + lq) ^ s7) << 3)];
                c = __builtin_amdgcn_mfma_f32_16x16x32_bf16(wf, xf[g], c, 0, 0, 0);
            }
            acc[k*2 + nt] = c;
        }
    }
    #undef PROJ_STAGE

    float ss = 0.f;
    #pragma unroll
    for (int q = 0; q < 16; ++q){
        #pragma unroll
        for (int r = 0; r < 4; ++r){ float x = acc[q][r]; ss += x*x; }
    }
    ss += __shfl_xor(ss, 16);
    ss += __shfl_xor(ss, 32);
    float scale = 1.0f / fmaxf(sqrtf(ss), 1e-12f);

    // dense epilogue via XOR-swizzled per-wave transpose bounce.
    // Wave w owns LDS rows [w*8, +8) of buf0+buf1 viewed as one 32KB region;
    // use rows w*16..w*16+15 across the two buffers: rows 0..7 in buf[0] region
    // offset (w*8), rows 8..15 in buf[1] region offset (w*8). Safe: after the
    // last barrier every wave only read buf1 (chunk 7); all of buf0 is idle,
    // and buf1 rows are re-written only by their owning wave (DS wave-ordered).
    {
        // writer: this lane's output row is l15 (0..15); e-column c per tile q
        int rsel = l15 >> 3;            // 0: buf0, 1: buf1
        int rloc = w*8 + (l15 & 7);
        short* twrow = &sW[rsel][rloc * 256];
        #pragma unroll
        for (int q = 0; q < 16; ++q){
            short4 pk;
            pk.x = f2bf(acc[q][0] * scale);
            pk.y = f2bf(acc[q][1] * scale);
            pk.z = f2bf(acc[q][2] * scale);
            pk.w = f2bf(acc[q][3] * scale);
            int c   = (q >> 2) * 64 + (q & 3) * 16 + lq*4;   // logical col (shorts)
            int blk = (c >> 3) ^ s7;                          // swizzled 16B block
            *(short4*)(twrow + blk*8 + (c & 7)) = pk;
        }
        // reader: output row r (0..15) = p*2 + (lane>>5); global block gblk = lane&31
        short* op = Out + (size_t)(row0 + w*16) * 256;
        #pragma unroll
        for (int p = 0; p < 8; ++p){
            int r    = p*2 + (lane >> 5);
            int gblk = lane & 31;
            const short* tr = &sW[r >> 3][(w*8 + (r & 7)) * 256 + ((gblk ^ (r & 7)) * 8)];
            *(int4*)(op + r*256 + gblk*8) = *(const int4*)tr;
        }
    }
}

// ---- loss: block = 128i x 256j; wave = 32 i-rows. E A-frags loaded ONCE.
// V staged in 8 chunks of 32 j-rows x K=256 (16KB) through a 2x16KB double
// buffer; issue-ahead pipeline. acc[2][2] flushed (exp) per chunk -> low VGPR.
// 32 KB LDS -> 4 blocks/CU. XCD-pinned grid 1024. psum[b][js][i], dense stores.
__global__ __launch_bounds__(256, 4) void loss_kernel(const short* __restrict__ E,
                                                      const short* __restrict__ V,
                                                      const float* __restrict__ cb,
                                                      float* __restrict__ psum){
    __shared__ short sV[2][32 * 256];   // 2 x 16KB, XOR-swizzled in 16B blocks
    __shared__ float sRed[4][32];

    // decode: xcd = n&7; m = n>>3 (0..127); b = (m>>5)*8 + xcd; lm = m&31
    int n  = blockIdx.x;
    int m  = n >> 3;
    int b  = ((m >> 5) << 3) | (n & 7);
    int lm = m & 31;
    int i0 = (lm >> 2) * 128;
    int js = lm & 3;
    int j0 = js * 256;

    int tid = threadIdx.x;
    int w = tid >> 6, lane = tid & 63;
    int l15 = lane & 15, lq = lane >> 4;
    int kb = lq * 8;
    int s7 = l15 & 7;
    int ro = lane >> 5;
    int cs = lane & 31;

    const short* Vbase = V + ((size_t)b*1024 + j0) * 256;

    #define LOSS_STAGE(ck, buf)                                                   \
        _Pragma("unroll")                                                         \
        for (int p = 0; p < 4; ++p){                                              \
            int rr = (p*2 + ro) & 7;                                              \
            gld16(Vbase + (size_t)((ck)*32 + w*8 + p*2 + ro)*256 + (cs ^ rr)*8,   \
                  &sV[buf][(w*8 + p*2) * 256]);                                   \
        }

    LOSS_STAGE(0, 0)
    LOSS_STAGE(1, 1)

    // A-frags: 2 sets x 8 -> 32 i-rows, register-resident, loaded once
    bf16x8 af[2][8];
    {
        const short* ep = E + ((size_t)b*1024 + i0 + w*32 + l15) * 256 + kb;
        #pragma unroll
        for (int g = 0; g < 8; ++g){
            af[0][g] = *(const bf16x8*)(ep + g*32);
            af[1][g] = *(const bf16x8*)(ep + 16*256 + g*32);
        }
    }

    // column-bias per j-tile ct (0..15): j = j0 + ct*16 + l15
    float cbv[16];
    #pragma unroll
    for (int ct = 0; ct < 16; ++ct)
        cbv[ct] = cb[b*1024 + j0 + ct*16 + l15];

    float ls[2][4] = {{0.f,0.f,0.f,0.f},{0.f,0.f,0.f,0.f}};

    __syncthreads();    // publish chunk 0 (and 1 in flight)

    #pragma unroll
    for (int k = 0; k < 8; ++k){
        if (k > 0) __syncthreads();
        if (k >= 1 && k < 7){ LOSS_STAGE(k+1, (k+1)&1) }
        f32x4 acc[2][2];
        #pragma unroll
        for (int s = 0; s < 2; ++s)
            #pragma unroll
            for (int jt = 0; jt < 2; ++jt) acc[s][jt] = (f32x4){0.f,0.f,0.f,0.f};
        #pragma unroll
        for (int jt = 0; jt < 2; ++jt){
            bf16x8 bfr[8];
            #pragma unroll
            for (int g = 0; g < 8; ++g)
                bfr[g] = *(const bf16x8*)&sV[k&1][(jt*16 + l15)*256 + (((g*4 + lq) ^ s7) << 3)];
            #pragma unroll
            for (int g = 0; g < 8; ++g){
                acc[0][jt] = __builtin_amdgcn_mfma_f32_16x16x32_bf16(af[0][g], bfr[g], acc[0][jt], 0, 0, 0);
                acc[1][jt] = __builtin_amdgcn_mfma_f32_16x16x32_bf16(af[1][g], bfr[g], acc[1][jt], 0, 0, 0);
            }
        }
        // flush: exp + accumulate into ls (each element exp'd exactly once)
        #pragma unroll
        for (int s = 0; s < 2; ++s){
            #pragma unroll
            for (int jt = 0; jt < 2; ++jt){
                float cbj = cbv[k*2 + jt];
                #pragma unroll
                for (int r = 0; r < 4; ++r)
                    ls[s][r] += __expf(fmaf(acc[s][jt][r], INVT, cbj));
            }
        }
    }
    #undef LOSS_STAGE

    // reduce over the 16 lanes sharing each row; dense store via LDS bounce
    #pragma unroll
    for (int s = 0; s < 2; ++s){
        #pragma unroll
        for (int r = 0; r < 4; ++r){
            float v = ls[s][r];
            #pragma unroll
            for (int mm = 1; mm < 16; mm <<= 1)
                v += __shfl_xor(v, mm);
            ls[s][r] = v;
        }
    }
    if (l15 == 0){
        #pragma unroll
        for (int s = 0; s < 2; ++s)
            #pragma unroll
            for (int r = 0; r < 4; ++r)
                sRed[w][s*16 + lq*4 + r] = ls[s][r];
    }
    float* pp = psum + (((size_t)(b*4 + js)) << 10);
    if (lane < 32) pp[i0 + w*32 + lane] = sRed[w][lane];
}

// ---- banded positive max: one 16-lane group per row, <=5 candidate cols via idx.
__global__ __launch_bounds__(256) void pos_kernel(const short* __restrict__ E,
                                                  const short* __restrict__ V,
                                                  const int* __restrict__ mask,
                                                  const int* __restrict__ rank,
                                                  const int* __restrict__ idx,
                                                  const int* __restrict__ Tv,
                                                  float* __restrict__ pmax){
    int tid = threadIdx.x;
    int gl  = tid & 15;
    int rf  = (blockIdx.x * 256 + tid) >> 4;   // 0..32767
    int b   = rf >> 10;
    if (mask[rf] <= 0) return;

    int ri = rank[rf];
    int tv = Tv[b];
    int lo = ri - 2; if (lo < 0) lo = 0;
    int hi = ri + 2; if (hi > tv - 1) hi = tv - 1;

    const short* epp = E + (size_t)rf * 256 + gl * 16;
    float ev[16];
    {
        bf16x8 e0 = *(const bf16x8*)epp;
        bf16x8 e1 = *(const bf16x8*)(epp + 8);
        #pragma unroll
        for (int k = 0; k < 8; ++k){ ev[k] = bf2f(e0[k]); ev[8+k] = bf2f(e1[k]); }
    }
    float pm = -1e30f;
    for (int r = lo; r <= hi; ++r){
        int j = idx[b*1024 + r];
        const short* vpp = V + ((size_t)(b*1024) + j) * 256 + gl * 16;
        bf16x8 v0 = *(const bf16x8*)vpp;
        bf16x8 v1 = *(const bf16x8*)(vpp + 8);
        float s = 0.f;
        #pragma unroll
        for (int k = 0; k < 8; ++k){
            s = fmaf(ev[k],   bf2f(v0[k]), s);
            s = fmaf(ev[8+k], bf2f(v1[k]), s);
        }
        s += __shfl_xor(s, 1);
        s += __shfl_xor(s, 2);
        s += __shfl_xor(s, 4);
        s += __shfl_xor(s, 8);
        pm = fmaxf(pm, s);
    }
    if (gl == 0) pmax[rf] = pm * INVT;
}

// ---- partial reduce: 4 blocks per b, each thread one i; coalesced psum reads.
__global__ __launch_bounds__(256) void reduce_kernel(const float* __restrict__ psum,
                                                     const float* __restrict__ pmax,
                                                     const int* __restrict__ mask,
                                                     float* __restrict__ bsum){
    int b  = blockIdx.x >> 2;
    int i  = (blockIdx.x & 3) * 256 + threadIdx.x;
    int g  = b*1024 + i;
    float a = 0.f;
    if (mask[g] > 0){
        const float* pp = psum + ((size_t)b << 12);
        float ps = pp[i] + pp[i + 1024] + pp[i + 2048] + pp[i + 3072];
        a = logf(ps) - pmax[g];
    }
    #pragma unroll
    for (int m = 1; m < 64; m <<= 1) a += __shfl_xor(a, m);
    if ((threadIdx.x & 63) == 0 && a != 0.f) atomicAdd(&bsum[b], a);
}

// ---- final: out = sum_b (Tv>=2 ? bsum/Tv : 0) / 32
__global__ void final_kernel(const float* __restrict__ bsum,
                             const int* __restrict__ Tv,
                             float* __restrict__ out){
    int tid = threadIdx.x;
    float v = 0.f;
    if (tid < 32){
        int tv = Tv[tid];
        if (tv >= 2) v = bsum[tid] / (float)tv;
    }
    #pragma unroll
    for (int m = 1; m < 64; m <<= 1) v += __shfl_xor(v, m);
    if (tid == 0) out[0] = v / 32.0f;
}

extern "C" void kernel_launch(void* const* d_in, const int* in_sizes, int n_in,
                              void* d_out, int out_size, void* d_ws, size_t ws_size,
                              hipStream_t stream) {
    const float* eeg  = (const float*)d_in[0];
    const float* eye  = (const float*)d_in[1];
    const int*   mask = (const int*)d_in[2];
    const float* Weeg = (const float*)d_in[3];
    const float* Weye = (const float*)d_in[4];
    float* out = (float*)d_out;

    char* ws = (char*)d_ws;
    short* e_bf  = (short*)(ws);                       // 16 MiB
    short* v_bf  = (short*)(ws + 16777216);            // 16 MiB
    short* wbf   = (short*)(ws + 33554432);            // 256 KiB
    int*   rank  = (int*)  (ws + 33816576);            // 128 KiB
    int*   idx   = (int*)  (ws + 33947648);            // 128 KiB
    float* cb    = (float*)(ws + 34078720);            // 128 KiB
    float* psum  = (float*)(ws + 34209792);            // 512 KiB (32 b x 4 slices x 1024 i)
    float* pmax  = (float*)(ws + 34734080);            // 128 KiB
    int*   Tv    = (int*)  (ws + 34865152);            // 128 B
    float* bsum  = (float*)(ws + 34865280);            // 128 B

    prep_kernel<<<544, 256, 0, stream>>>(Weeg, Weye, mask, wbf, rank, idx, Tv, cb, bsum);
    proj_kernel<<<dim3(512, 2), 256, 0, stream>>>(eeg, eye, wbf, e_bf, v_bf);
    loss_kernel<<<1024, 256, 0, stream>>>(e_bf, v_bf, cb, psum);
    pos_kernel<<<2048, 256, 0, stream>>>(e_bf, v_bf, mask, rank, idx, Tv, pmax);
    reduce_kernel<<<128, 256, 0, stream>>>(psum, pmax, mask, bsum);
    final_kernel<<<1, 64, 0, stream>>>(bsum, Tv, out);
}

// Round 14
// 184.851 us; speedup vs baseline: 1.2610x; 1.2610x over previous
//
#include <hip/hip_runtime.h>
#include <hip/hip_bf16.h>

// B=32, T=1024, D=256 fixed by the reference problem.
typedef __attribute__((ext_vector_type(8))) short bf16x8;
typedef __attribute__((ext_vector_type(4))) float f32x4;

#define INVT (1.0f/0.07f)

static __device__ __forceinline__ short f2bf(float f){
    unsigned int u = __float_as_uint(f);
    unsigned int r = (u + 0x7fffu + ((u >> 16) & 1u)) >> 16;
    return (short)r;
}
static __device__ __forceinline__ float bf2f(short s){
    return __uint_as_float(((unsigned int)(unsigned short)s) << 16);
}

// async global->LDS, 16B per lane; LDS dest = wave-uniform base + lane*16
static __device__ __forceinline__ void gld16(const void* g, void* l){
    __builtin_amdgcn_global_load_lds(
        (const __attribute__((address_space(1))) unsigned int*)g,
        (__attribute__((address_space(3))) unsigned int*)l, 16, 0, 0);
}

// ---- prep: blocks 0..511 convert W to bf16; blocks 512..543 per-batch rank scan + zero bsum
__global__ __launch_bounds__(256) void prep_kernel(const float* __restrict__ Weeg,
                                                   const float* __restrict__ Weye,
                                                   const int* __restrict__ mask,
                                                   short* __restrict__ Wout,
                                                   int* __restrict__ rank,
                                                   int* __restrict__ idx,
                                                   int* __restrict__ Tv,
                                                   float* __restrict__ cb,
                                                   float* __restrict__ bsum){
    __shared__ int ssum[256];
    int tid = threadIdx.x;
    if (blockIdx.x < 512){
        int i = blockIdx.x * 256 + tid;
        float v = (i < 65536) ? Weeg[i] : Weye[i - 65536];
        Wout[i] = f2bf(v);
        return;
    }
    int b = blockIdx.x - 512;
    if (tid == 0) bsum[b] = 0.f;
    int local[4]; int s = 0;
    #pragma unroll
    for (int q = 0; q < 4; ++q){
        int t = tid*4 + q;
        local[q] = (mask[b*1024 + t] > 0) ? 1 : 0;
        s += local[q];
    }
    ssum[tid] = s;
    __syncthreads();
    for (int off = 1; off < 256; off <<= 1){
        int add = (tid >= off) ? ssum[tid - off] : 0;
        __syncthreads();
        ssum[tid] += add;
        __syncthreads();
    }
    int run = ssum[tid] - s;
    #pragma unroll
    for (int q = 0; q < 4; ++q){
        int t = tid*4 + q;
        int g = b*1024 + t;
        run += local[q];
        rank[g] = run - 1;
        cb[g]   = local[q] ? 0.0f : -1e9f;
        if (local[q]) idx[b*1024 + run - 1] = t;
    }
    if (tid == 255) Tv[b] = ssum[255];
}

// ---- fused projection + L2 normalize, both modalities (blockIdx.y selects).
// 2 x 16KB double-buffered W staging, 8 chunks of 32 W-rows, issue-ahead
// pipeline. launch_bounds(256,3): VGPR budget ~170 -> no spills; LDS allows 4
// blocks/CU, VGPR allows 3 -> 3 blocks/CU (vs 2 at R12's 64 KB).
__global__ __launch_bounds__(256, 3) void proj_kernel(const float* __restrict__ Aeeg,
                                                      const float* __restrict__ Aeye,
                                                      const short* __restrict__ Wbf,
                                                      short* __restrict__ Eout,
                                                      short* __restrict__ Vout){
    __shared__ short sW[2][32 * 256];   // 2 x 16KB, XOR-swizzled in 16B blocks
    int sel = blockIdx.y;
    const float* A   = sel ? Aeye : Aeeg;
    const short* W   = Wbf + sel * 65536;
    short*       Out = sel ? Vout : Eout;

    int tid = threadIdx.x;
    int w = tid >> 6, lane = tid & 63;
    int l15 = lane & 15, lq = lane >> 4;
    int kb  = lq * 8;
    int row0 = blockIdx.x * 64;

    int ro   = lane >> 5;        // 0..1: row within a 1KB gld16 issue
    int cs   = lane & 31;        // 16B col-block within a 512B row
    int s7   = l15 & 7;

    // stage chunk ck (32 W-rows) into buf: wave w covers rows [w*8, +8), 4 issues
    #define PROJ_STAGE(ck, buf)                                              \
        _Pragma("unroll")                                                    \
        for (int p = 0; p < 4; ++p){                                         \
            int rr = (p*2 + ro) & 7;                                         \
            gld16(W + (size_t)((ck)*32 + w*8 + p*2 + ro)*256 + (cs ^ rr)*8,  \
                  &sW[buf][(w*8 + p*2) * 256]);                              \
        }

    PROJ_STAGE(0, 0)
    PROJ_STAGE(1, 1)

    // X-row fragments (B-operand), f32 -> bf16 (HBM; drains with chunk0/1)
    bf16x8 xf[8];
    {
        const float* ap = A + (size_t)(row0 + w*16 + l15) * 256 + kb;
        #pragma unroll
        for (int g = 0; g < 8; ++g){
            float4 x0 = *(const float4*)(ap + g*32);
            float4 x1 = *(const float4*)(ap + g*32 + 4);
            bf16x8 t;
            t[0]=f2bf(x0.x); t[1]=f2bf(x0.y); t[2]=f2bf(x0.z); t[3]=f2bf(x0.w);
            t[4]=f2bf(x1.x); t[5]=f2bf(x1.y); t[6]=f2bf(x1.z); t[7]=f2bf(x1.w);
            xf[g] = t;
        }
    }

    f32x4 acc[16];
    #pragma unroll
    for (int q = 0; q < 16; ++q) acc[q] = (f32x4){0.f,0.f,0.f,0.f};

    __syncthreads();   // c0, c1, xf ready

    // compute chunk 0 (e-tiles 0..1) from buf0
    #pragma unroll
    for (int nt = 0; nt < 2; ++nt){
        f32x4 c = acc[nt];
        int rbase = (nt*16 + l15) * 256;
        #pragma unroll
        for (int g = 0; g < 8; ++g){
            bf16x8 wf = *(const bf16x8*)&sW[0][rbase + (((g*4 + lq) ^ s7) << 3)];
            c = __builtin_amdgcn_mfma_f32_16x16x32_bf16(wf, xf[g], c, 0, 0, 0);
        }
        acc[nt] = c;
    }

    // chunks 1..7: sync; issue k+1; compute k
    #pragma unroll
    for (int k = 1; k < 8; ++k){
        __syncthreads();
        if (k < 7){ PROJ_STAGE(k+1, (k+1)&1) }
        #pragma unroll
        for (int nt = 0; nt < 2; ++nt){
            f32x4 c = acc[k*2 + nt];
            int rbase = (nt*16 + l15) * 256;
            #pragma unroll
            for (int g = 0; g < 8; ++g){
                bf16x8 wf = *(const bf16x8*)&sW[k&1][rbase + (((g*4 + lq) ^ s7) << 3)];
                c = __builtin_amdgcn_mfma_f32_16x16x32_bf16(wf, xf[g], c, 0, 0, 0);
            }
            acc[k*2 + nt] = c;
        }
    }
    #undef PROJ_STAGE

    float ss = 0.f;
    #pragma unroll
    for (int q = 0; q < 16; ++q){
        #pragma unroll
        for (int r = 0; r < 4; ++r){ float x = acc[q][r]; ss += x*x; }
    }
    ss += __shfl_xor(ss, 16);
    ss += __shfl_xor(ss, 32);
    float scale = 1.0f / fmaxf(sqrtf(ss), 1e-12f);

    // dense epilogue via XOR-swizzled per-wave transpose bounce (both 16KB bufs
    // viewed as one region; safe: after last barrier chunk-7 compute reads buf1
    // rows only via this wave's own reads; DS ops wave-ordered).
    {
        int rsel = l15 >> 3;            // 0: buf0, 1: buf1
        int rloc = w*8 + (l15 & 7);
        short* twrow = &sW[rsel][rloc * 256];
        #pragma unroll
        for (int q = 0; q < 16; ++q){
            short4 pk;
            pk.x = f2bf(acc[q][0] * scale);
            pk.y = f2bf(acc[q][1] * scale);
            pk.z = f2bf(acc[q][2] * scale);
            pk.w = f2bf(acc[q][3] * scale);
            int c   = (q >> 2) * 64 + (q & 3) * 16 + lq*4;   // logical col (shorts)
            int blk = (c >> 3) ^ s7;                          // swizzled 16B block
            *(short4*)(twrow + blk*8 + (c & 7)) = pk;
        }
        short* op = Out + (size_t)(row0 + w*16) * 256;
        #pragma unroll
        for (int p = 0; p < 8; ++p){
            int r    = p*2 + (lane >> 5);
            int gblk = lane & 31;
            const short* tr = &sW[r >> 3][(w*8 + (r & 7)) * 256 + ((gblk ^ (r & 7)) * 8)];
            *(int4*)(op + r*256 + gblk*8) = *(const int4*)tr;
        }
    }
}

// ---- loss: block = 128i x 256j; wave = 32 i-rows. E A-frags loaded ONCE.
// V staged in 8 chunks of 32 j-rows x K=256 (16KB) through a 2x16KB double
// buffer; issue-ahead pipeline; exp-flush per chunk. launch_bounds(256,3):
// no spills, 3 blocks/CU. XCD-pinned grid 1024. psum[b][js][i], dense stores.
__global__ __launch_bounds__(256, 3) void loss_kernel(const short* __restrict__ E,
                                                      const short* __restrict__ V,
                                                      const float* __restrict__ cb,
                                                      float* __restrict__ psum){
    __shared__ short sV[2][32 * 256];   // 2 x 16KB, XOR-swizzled in 16B blocks
    __shared__ float sRed[4][32];

    // decode: xcd = n&7; m = n>>3 (0..127); b = (m>>5)*8 + xcd; lm = m&31
    int n  = blockIdx.x;
    int m  = n >> 3;
    int b  = ((m >> 5) << 3) | (n & 7);
    int lm = m & 31;
    int i0 = (lm >> 2) * 128;
    int js = lm & 3;
    int j0 = js * 256;

    int tid = threadIdx.x;
    int w = tid >> 6, lane = tid & 63;
    int l15 = lane & 15, lq = lane >> 4;
    int kb = lq * 8;
    int s7 = l15 & 7;
    int ro = lane >> 5;
    int cs = lane & 31;

    const short* Vbase = V + ((size_t)b*1024 + j0) * 256;

    #define LOSS_STAGE(ck, buf)                                                   \
        _Pragma("unroll")                                                         \
        for (int p = 0; p < 4; ++p){                                              \
            int rr = (p*2 + ro) & 7;                                              \
            gld16(Vbase + (size_t)((ck)*32 + w*8 + p*2 + ro)*256 + (cs ^ rr)*8,   \
                  &sV[buf][(w*8 + p*2) * 256]);                                   \
        }

    LOSS_STAGE(0, 0)
    LOSS_STAGE(1, 1)

    // A-frags: 2 sets x 8 -> 32 i-rows, register-resident, loaded once
    bf16x8 af[2][8];
    {
        const short* ep = E + ((size_t)b*1024 + i0 + w*32 + l15) * 256 + kb;
        #pragma unroll
        for (int g = 0; g < 8; ++g){
            af[0][g] = *(const bf16x8*)(ep + g*32);
            af[1][g] = *(const bf16x8*)(ep + 16*256 + g*32);
        }
    }

    // column-bias per j-tile ct (0..15): j = j0 + ct*16 + l15
    float cbv[16];
    #pragma unroll
    for (int ct = 0; ct < 16; ++ct)
        cbv[ct] = cb[b*1024 + j0 + ct*16 + l15];

    float ls[2][4] = {{0.f,0.f,0.f,0.f},{0.f,0.f,0.f,0.f}};

    __syncthreads();    // publish chunk 0 (and 1 in flight)

    #pragma unroll
    for (int k = 0; k < 8; ++k){
        if (k > 0) __syncthreads();
        if (k >= 1 && k < 7){ LOSS_STAGE(k+1, (k+1)&1) }
        f32x4 acc[2][2];
        #pragma unroll
        for (int s = 0; s < 2; ++s)
            #pragma unroll
            for (int jt = 0; jt < 2; ++jt) acc[s][jt] = (f32x4){0.f,0.f,0.f,0.f};
        #pragma unroll
        for (int jt = 0; jt < 2; ++jt){
            bf16x8 bfr[8];
            #pragma unroll
            for (int g = 0; g < 8; ++g)
                bfr[g] = *(const bf16x8*)&sV[k&1][(jt*16 + l15)*256 + (((g*4 + lq) ^ s7) << 3)];
            #pragma unroll
            for (int g = 0; g < 8; ++g){
                acc[0][jt] = __builtin_amdgcn_mfma_f32_16x16x32_bf16(af[0][g], bfr[g], acc[0][jt], 0, 0, 0);
                acc[1][jt] = __builtin_amdgcn_mfma_f32_16x16x32_bf16(af[1][g], bfr[g], acc[1][jt], 0, 0, 0);
            }
        }
        // flush: exp + accumulate into ls (each element exp'd exactly once)
        #pragma unroll
        for (int s = 0; s < 2; ++s){
            #pragma unroll
            for (int jt = 0; jt < 2; ++jt){
                float cbj = cbv[k*2 + jt];
                #pragma unroll
                for (int r = 0; r < 4; ++r)
                    ls[s][r] += __expf(fmaf(acc[s][jt][r], INVT, cbj));
            }
        }
    }
    #undef LOSS_STAGE

    // reduce over the 16 lanes sharing each row; dense store via LDS bounce
    #pragma unroll
    for (int s = 0; s < 2; ++s){
        #pragma unroll
        for (int r = 0; r < 4; ++r){
            float v = ls[s][r];
            #pragma unroll
            for (int mm = 1; mm < 16; mm <<= 1)
                v += __shfl_xor(v, mm);
            ls[s][r] = v;
        }
    }
    if (l15 == 0){
        #pragma unroll
        for (int s = 0; s < 2; ++s)
            #pragma unroll
            for (int r = 0; r < 4; ++r)
                sRed[w][s*16 + lq*4 + r] = ls[s][r];
    }
    float* pp = psum + (((size_t)(b*4 + js)) << 10);
    if (lane < 32) pp[i0 + w*32 + lane] = sRed[w][lane];
}

// ---- banded positive max: one 16-lane group per row, <=5 candidate cols via idx.
__global__ __launch_bounds__(256) void pos_kernel(const short* __restrict__ E,
                                                  const short* __restrict__ V,
                                                  const int* __restrict__ mask,
                                                  const int* __restrict__ rank,
                                                  const int* __restrict__ idx,
                                                  const int* __restrict__ Tv,
                                                  float* __restrict__ pmax){
    int tid = threadIdx.x;
    int gl  = tid & 15;
    int rf  = (blockIdx.x * 256 + tid) >> 4;   // 0..32767
    int b   = rf >> 10;
    if (mask[rf] <= 0) return;

    int ri = rank[rf];
    int tv = Tv[b];
    int lo = ri - 2; if (lo < 0) lo = 0;
    int hi = ri + 2; if (hi > tv - 1) hi = tv - 1;

    const short* epp = E + (size_t)rf * 256 + gl * 16;
    float ev[16];
    {
        bf16x8 e0 = *(const bf16x8*)epp;
        bf16x8 e1 = *(const bf16x8*)(epp + 8);
        #pragma unroll
        for (int k = 0; k < 8; ++k){ ev[k] = bf2f(e0[k]); ev[8+k] = bf2f(e1[k]); }
    }
    float pm = -1e30f;
    for (int r = lo; r <= hi; ++r){
        int j = idx[b*1024 + r];
        const short* vpp = V + ((size_t)(b*1024) + j) * 256 + gl * 16;
        bf16x8 v0 = *(const bf16x8*)vpp;
        bf16x8 v1 = *(const bf16x8*)(vpp + 8);
        float s = 0.f;
        #pragma unroll
        for (int k = 0; k < 8; ++k){
            s = fmaf(ev[k],   bf2f(v0[k]), s);
            s = fmaf(ev[8+k], bf2f(v1[k]), s);
        }
        s += __shfl_xor(s, 1);
        s += __shfl_xor(s, 2);
        s += __shfl_xor(s, 4);
        s += __shfl_xor(s, 8);
        pm = fmaxf(pm, s);
    }
    if (gl == 0) pmax[rf] = pm * INVT;
}

// ---- partial reduce: 4 blocks per b, each thread one i; coalesced psum reads.
__global__ __launch_bounds__(256) void reduce_kernel(const float* __restrict__ psum,
                                                     const float* __restrict__ pmax,
                                                     const int* __restrict__ mask,
                                                     float* __restrict__ bsum){
    int b  = blockIdx.x >> 2;
    int i  = (blockIdx.x & 3) * 256 + threadIdx.x;
    int g  = b*1024 + i;
    float a = 0.f;
    if (mask[g] > 0){
        const float* pp = psum + ((size_t)b << 12);
        float ps = pp[i] + pp[i + 1024] + pp[i + 2048] + pp[i + 3072];
        a = logf(ps) - pmax[g];
    }
    #pragma unroll
    for (int m = 1; m < 64; m <<= 1) a += __shfl_xor(a, m);
    if ((threadIdx.x & 63) == 0 && a != 0.f) atomicAdd(&bsum[b], a);
}

// ---- final: out = sum_b (Tv>=2 ? bsum/Tv : 0) / 32
__global__ void final_kernel(const float* __restrict__ bsum,
                             const int* __restrict__ Tv,
                             float* __restrict__ out){
    int tid = threadIdx.x;
    float v = 0.f;
    if (tid < 32){
        int tv = Tv[tid];
        if (tv >= 2) v = bsum[tid] / (float)tv;
    }
    #pragma unroll
    for (int m = 1; m < 64; m <<= 1) v += __shfl_xor(v, m);
    if (tid == 0) out[0] = v / 32.0f;
}

extern "C" void kernel_launch(void* const* d_in, const int* in_sizes, int n_in,
                              void* d_out, int out_size, void* d_ws, size_t ws_size,
                              hipStream_t stream) {
    const float* eeg  = (const float*)d_in[0];
    const float* eye  = (const float*)d_in[1];
    const int*   mask = (const int*)d_in[2];
    const float* Weeg = (const float*)d_in[3];
    const float* Weye = (const float*)d_in[4];
    float* out = (float*)d_out;

    char* ws = (char*)d_ws;
    short* e_bf  = (short*)(ws);                       // 16 MiB
    short* v_bf  = (short*)(ws + 16777216);            // 16 MiB
    short* wbf   = (short*)(ws + 33554432);            // 256 KiB
    int*   rank  = (int*)  (ws + 33816576);            // 128 KiB
    int*   idx   = (int*)  (ws + 33947648);            // 128 KiB
    float* cb    = (float*)(ws + 34078720);            // 128 KiB
    float* psum  = (float*)(ws + 34209792);            // 512 KiB (32 b x 4 slices x 1024 i)
    float* pmax  = (float*)(ws + 34734080);            // 128 KiB
    int*   Tv    = (int*)  (ws + 34865152);            // 128 B
    float* bsum  = (float*)(ws + 34865280);            // 128 B

    prep_kernel<<<544, 256, 0, stream>>>(Weeg, Weye, mask, wbf, rank, idx, Tv, cb, bsum);
    proj_kernel<<<dim3(512, 2), 256, 0, stream>>>(eeg, eye, wbf, e_bf, v_bf);
    loss_kernel<<<1024, 256, 0, stream>>>(e_bf, v_bf, cb, psum);
    pos_kernel<<<2048, 256, 0, stream>>>(e_bf, v_bf, mask, rank, idx, Tv, pmax);
    reduce_kernel<<<128, 256, 0, stream>>>(psum, pmax, mask, bsum);
    final_kernel<<<1, 64, 0, stream>>>(bsum, Tv, out);
}

// Round 15
// 157.682 us; speedup vs baseline: 1.4783x; 1.1723x over previous
//
#include <hip/hip_runtime.h>
#include <hip/hip_bf16.h>

// B=32, T=1024, D=256 fixed by the reference problem.
typedef __attribute__((ext_vector_type(8))) short bf16x8;
typedef __attribute__((ext_vector_type(4))) float f32x4;

#define INVT (1.0f/0.07f)

static __device__ __forceinline__ short f2bf(float f){
    unsigned int u = __float_as_uint(f);
    unsigned int r = (u + 0x7fffu + ((u >> 16) & 1u)) >> 16;
    return (short)r;
}
static __device__ __forceinline__ float bf2f(short s){
    return __uint_as_float(((unsigned int)(unsigned short)s) << 16);
}

// async global->LDS, 16B per lane; LDS dest = wave-uniform base + lane*16
static __device__ __forceinline__ void gld16(const void* g, void* l){
    __builtin_amdgcn_global_load_lds(
        (const __attribute__((address_space(1))) unsigned int*)g,
        (__attribute__((address_space(3))) unsigned int*)l, 16, 0, 0);
}

// ---- prep: blocks 0..511 convert W to bf16; blocks 512..543 per-batch rank scan + zero bsum
__global__ __launch_bounds__(256) void prep_kernel(const float* __restrict__ Weeg,
                                                   const float* __restrict__ Weye,
                                                   const int* __restrict__ mask,
                                                   short* __restrict__ Wout,
                                                   int* __restrict__ rank,
                                                   int* __restrict__ idx,
                                                   int* __restrict__ Tv,
                                                   float* __restrict__ cb,
                                                   float* __restrict__ bsum){
    __shared__ int ssum[256];
    int tid = threadIdx.x;
    if (blockIdx.x < 512){
        int i = blockIdx.x * 256 + tid;
        float v = (i < 65536) ? Weeg[i] : Weye[i - 65536];
        Wout[i] = f2bf(v);
        return;
    }
    int b = blockIdx.x - 512;
    if (tid == 0) bsum[b] = 0.f;
    int local[4]; int s = 0;
    #pragma unroll
    for (int q = 0; q < 4; ++q){
        int t = tid*4 + q;
        local[q] = (mask[b*1024 + t] > 0) ? 1 : 0;
        s += local[q];
    }
    ssum[tid] = s;
    __syncthreads();
    for (int off = 1; off < 256; off <<= 1){
        int add = (tid >= off) ? ssum[tid - off] : 0;
        __syncthreads();
        ssum[tid] += add;
        __syncthreads();
    }
    int run = ssum[tid] - s;
    #pragma unroll
    for (int q = 0; q < 4; ++q){
        int t = tid*4 + q;
        int g = b*1024 + t;
        run += local[q];
        rank[g] = run - 1;
        cb[g]   = local[q] ? 0.0f : -1e9f;
        if (local[q]) idx[b*1024 + run - 1] = t;
    }
    if (tid == 255) Tv[b] = ssum[255];
}

// ---- fused projection + L2 normalize, both modalities (blockIdx.y selects).
// Double-buffered W staging (2 x 32KB), 4 chunks of 64 W-rows, drains overlapped.
// Dense epilogue via XOR-swizzled per-wave LDS transpose bounce (conflict-free)
// -> coalesced 16B/lane stores.
__global__ __launch_bounds__(256, 2) void proj_kernel(const float* __restrict__ Aeeg,
                                                      const float* __restrict__ Aeye,
                                                      const short* __restrict__ Wbf,
                                                      short* __restrict__ Eout,
                                                      short* __restrict__ Vout){
    __shared__ short sW[2][64 * 256];   // 2 x 32KB, XOR-swizzled in 16B blocks
    int sel = blockIdx.y;
    const float* A   = sel ? Aeye : Aeeg;
    const short* W   = Wbf + sel * 65536;
    short*       Out = sel ? Vout : Eout;

    int tid = threadIdx.x;
    int w = tid >> 6, lane = tid & 63;
    int l15 = lane & 15, lq = lane >> 4;
    int kb  = lq * 8;
    int row0 = blockIdx.x * 64;

    int ro   = lane >> 5;
    int cs   = lane & 31;
    int s7   = l15 & 7;

    // issue chunk 0 (W rows 0..63) -> buf0 and chunk 1 (64..127) -> buf1
    #pragma unroll
    for (int p = 0; p < 8; ++p){
        int rr = (p*2 + ro) & 7;
        gld16(W + (size_t)(w*16 + p*2 + ro)*256 + (cs ^ rr)*8,
              &sW[0][(w*16 + p*2) * 256]);
    }
    #pragma unroll
    for (int p = 0; p < 8; ++p){
        int rr = (p*2 + ro) & 7;
        gld16(W + (size_t)(64 + w*16 + p*2 + ro)*256 + (cs ^ rr)*8,
              &sW[1][(w*16 + p*2) * 256]);
    }

    // X-row fragments (B-operand), f32 -> bf16 (HBM; drains with chunk0/1)
    bf16x8 xf[8];
    {
        const float* ap = A + (size_t)(row0 + w*16 + l15) * 256 + kb;
        #pragma unroll
        for (int g = 0; g < 8; ++g){
            float4 x0 = *(const float4*)(ap + g*32);
            float4 x1 = *(const float4*)(ap + g*32 + 4);
            bf16x8 t;
            t[0]=f2bf(x0.x); t[1]=f2bf(x0.y); t[2]=f2bf(x0.z); t[3]=f2bf(x0.w);
            t[4]=f2bf(x1.x); t[5]=f2bf(x1.y); t[6]=f2bf(x1.z); t[7]=f2bf(x1.w);
            xf[g] = t;
        }
    }

    f32x4 acc[16];
    #pragma unroll
    for (int q = 0; q < 16; ++q) acc[q] = (f32x4){0.f,0.f,0.f,0.f};

    __syncthreads();   // c0, c1, xf ready

    #pragma unroll
    for (int nt = 0; nt < 4; ++nt){
        f32x4 c = acc[nt];
        int rbase = (nt*16 + l15) * 256;
        #pragma unroll
        for (int g = 0; g < 8; ++g){
            bf16x8 wf = *(const bf16x8*)&sW[0][rbase + (((g*4 + lq) ^ s7) << 3)];
            c = __builtin_amdgcn_mfma_f32_16x16x32_bf16(wf, xf[g], c, 0, 0, 0);
        }
        acc[nt] = c;
    }

    __syncthreads();

    #pragma unroll
    for (int p = 0; p < 8; ++p){
        int rr = (p*2 + ro) & 7;
        gld16(W + (size_t)(128 + w*16 + p*2 + ro)*256 + (cs ^ rr)*8,
              &sW[0][(w*16 + p*2) * 256]);
    }
    #pragma unroll
    for (int nt = 0; nt < 4; ++nt){
        f32x4 c = acc[4 + nt];
        int rbase = (nt*16 + l15) * 256;
        #pragma unroll
        for (int g = 0; g < 8; ++g){
            bf16x8 wf = *(const bf16x8*)&sW[1][rbase + (((g*4 + lq) ^ s7) << 3)];
            c = __builtin_amdgcn_mfma_f32_16x16x32_bf16(wf, xf[g], c, 0, 0, 0);
        }
        acc[4 + nt] = c;
    }

    __syncthreads();

    #pragma unroll
    for (int p = 0; p < 8; ++p){
        int rr = (p*2 + ro) & 7;
        gld16(W + (size_t)(192 + w*16 + p*2 + ro)*256 + (cs ^ rr)*8,
              &sW[1][(w*16 + p*2) * 256]);
    }
    #pragma unroll
    for (int nt = 0; nt < 4; ++nt){
        f32x4 c = acc[8 + nt];
        int rbase = (nt*16 + l15) * 256;
        #pragma unroll
        for (int g = 0; g < 8; ++g){
            bf16x8 wf = *(const bf16x8*)&sW[0][rbase + (((g*4 + lq) ^ s7) << 3)];
            c = __builtin_amdgcn_mfma_f32_16x16x32_bf16(wf, xf[g], c, 0, 0, 0);
        }
        acc[8 + nt] = c;
    }

    __syncthreads();

    #pragma unroll
    for (int nt = 0; nt < 4; ++nt){
        f32x4 c = acc[12 + nt];
        int rbase = (nt*16 + l15) * 256;
        #pragma unroll
        for (int g = 0; g < 8; ++g){
            bf16x8 wf = *(const bf16x8*)&sW[1][rbase + (((g*4 + lq) ^ s7) << 3)];
            c = __builtin_amdgcn_mfma_f32_16x16x32_bf16(wf, xf[g], c, 0, 0, 0);
        }
        acc[12 + nt] = c;
    }

    float ss = 0.f;
    #pragma unroll
    for (int q = 0; q < 16; ++q){
        #pragma unroll
        for (int r = 0; r < 4; ++r){ float x = acc[q][r]; ss += x*x; }
    }
    ss += __shfl_xor(ss, 16);
    ss += __shfl_xor(ss, 32);
    float scale = 1.0f / fmaxf(sqrtf(ss), 1e-12f);

    // dense epilogue via XOR-swizzled per-wave transpose bounce through buf0.
    short* twrow = &sW[0][(w*16 + l15) * 256];
    #pragma unroll
    for (int q = 0; q < 16; ++q){
        short4 pk;
        pk.x = f2bf(acc[q][0] * scale);
        pk.y = f2bf(acc[q][1] * scale);
        pk.z = f2bf(acc[q][2] * scale);
        pk.w = f2bf(acc[q][3] * scale);
        int c    = (q >> 2) * 64 + (q & 3) * 16 + lq*4;   // logical column (shorts)
        int blk  = (c >> 3) ^ s7;                          // swizzled 16B block
        *(short4*)(twrow + blk*8 + (c & 7)) = pk;
    }
    short* op = Out + (size_t)(row0 + w*16) * 256;
    #pragma unroll
    for (int p = 0; p < 8; ++p){
        int rloc = p*2 + (lane >> 5);
        int gblk = lane & 31;
        const short* tr = &sW[0][(w*16 + rloc) * 256 + ((gblk ^ (rloc & 7)) * 8)];
        *(int4*)(op + rloc*256 + gblk*8) = *(const int4*)tr;
    }
}

// ---- loss: block = 128i x 256j; wave = 32 i-rows. E A-frags loaded ONCE per
// 256-j sweep. V staged in 4 chunks of 64 j-rows x K=256 (32KB) through a
// 2x32KB double buffer; 4 barriers, drains overlapped. XCD-pinned grid 1024.
// Epilogue -> psum[b][js][i] (4 slices), dense stores.
__global__ __launch_bounds__(256, 2) void loss_kernel(const short* __restrict__ E,
                                                      const short* __restrict__ V,
                                                      const float* __restrict__ cb,
                                                      float* __restrict__ psum){
    __shared__ short sV[2][64 * 256];   // 2 x 32KB, XOR-swizzled in 16B blocks
    __shared__ float sRed[4][32];

    int n  = blockIdx.x;
    int m  = n >> 3;
    int b  = ((m >> 5) << 3) | (n & 7);
    int lm = m & 31;
    int i0 = (lm >> 2) * 128;
    int js = lm & 3;
    int j0 = js * 256;

    int tid = threadIdx.x;
    int w = tid >> 6, lane = tid & 63;
    int l15 = lane & 15, lq = lane >> 4;
    int kb = lq * 8;
    int s7 = l15 & 7;
    int ro = lane >> 5;
    int cs = lane & 31;

    const short* Vrow = V + ((size_t)b*1024 + j0 + w*16 + ro) * 256;

    // issue h0c0 (j rows 0..63) -> buf0
    #pragma unroll
    for (int p = 0; p < 8; ++p){
        int rr = (p*2 + ro) & 7;
        gld16(Vrow + (size_t)(p*2)*256 + (size_t)((cs ^ rr) * 8),
              &sV[0][(w*16 + p*2) * 256]);
    }

    // A-frags: 2 sets x 8 -> 32 i-rows, register-resident, loaded once
    bf16x8 af[2][8];
    {
        const short* ep = E + ((size_t)b*1024 + i0 + w*32 + l15) * 256 + kb;
        #pragma unroll
        for (int g = 0; g < 8; ++g){
            af[0][g] = *(const bf16x8*)(ep + g*32);
            af[1][g] = *(const bf16x8*)(ep + 16*256 + g*32);
        }
    }

    float cbv0[8];
    #pragma unroll
    for (int ct = 0; ct < 8; ++ct)
        cbv0[ct] = cb[b*1024 + j0 + ct*16 + l15];

    f32x4 acc[2][8];
    #pragma unroll
    for (int s = 0; s < 2; ++s)
        #pragma unroll
        for (int ct = 0; ct < 8; ++ct) acc[s][ct] = (f32x4){0.f,0.f,0.f,0.f};
    float ls[2][4] = {{0.f,0.f,0.f,0.f},{0.f,0.f,0.f,0.f}};

    __syncthreads();    // publish h0c0

    // issue h0c1 (64..127) -> buf1
    #pragma unroll
    for (int p = 0; p < 8; ++p){
        int rr = (p*2 + ro) & 7;
        gld16(Vrow + (size_t)(64 + p*2)*256 + (size_t)((cs ^ rr) * 8),
              &sV[1][(w*16 + p*2) * 256]);
    }
    // compute h0c0 from buf0
    #pragma unroll
    for (int jt = 0; jt < 4; ++jt){
        bf16x8 bf[8];
        #pragma unroll
        for (int g = 0; g < 8; ++g)
            bf[g] = *(const bf16x8*)&sV[0][(jt*16 + l15)*256 + (((g*4 + lq) ^ s7) << 3)];
        #pragma unroll
        for (int g = 0; g < 8; ++g){
            acc[0][jt] = __builtin_amdgcn_mfma_f32_16x16x32_bf16(af[0][g], bf[g], acc[0][jt], 0, 0, 0);
            acc[1][jt] = __builtin_amdgcn_mfma_f32_16x16x32_bf16(af[1][g], bf[g], acc[1][jt], 0, 0, 0);
        }
    }

    __syncthreads();    // publish h0c1 (drain overlapped by h0c0 compute)

    // issue h1c0 (128..191) -> buf0
    #pragma unroll
    for (int p = 0; p < 8; ++p){
        int rr = (p*2 + ro) & 7;
        gld16(Vrow + (size_t)(128 + p*2)*256 + (size_t)((cs ^ rr) * 8),
              &sV[0][(w*16 + p*2) * 256]);
    }
    // compute h0c1 from buf1
    #pragma unroll
    for (int jt = 0; jt < 4; ++jt){
        bf16x8 bf[8];
        #pragma unroll
        for (int g = 0; g < 8; ++g)
            bf[g] = *(const bf16x8*)&sV[1][(jt*16 + l15)*256 + (((g*4 + lq) ^ s7) << 3)];
        #pragma unroll
        for (int g = 0; g < 8; ++g){
            acc[0][4+jt] = __builtin_amdgcn_mfma_f32_16x16x32_bf16(af[0][g], bf[g], acc[0][4+jt], 0, 0, 0);
            acc[1][4+jt] = __builtin_amdgcn_mfma_f32_16x16x32_bf16(af[1][g], bf[g], acc[1][4+jt], 0, 0, 0);
        }
    }
    // epilogue-accumulate half0 (overlaps h1c0 drain), then reset acc
    #pragma unroll
    for (int s = 0; s < 2; ++s){
        #pragma unroll
        for (int r = 0; r < 4; ++r){
            float a0 = 0.f;
            #pragma unroll
            for (int ct = 0; ct < 8; ++ct)
                a0 += __expf(fmaf(acc[s][ct][r], INVT, cbv0[ct]));
            ls[s][r] += a0;
        }
    }
    #pragma unroll
    for (int s = 0; s < 2; ++s)
        #pragma unroll
        for (int ct = 0; ct < 8; ++ct) acc[s][ct] = (f32x4){0.f,0.f,0.f,0.f};

    float cbv1[8];
    #pragma unroll
    for (int ct = 0; ct < 8; ++ct)
        cbv1[ct] = cb[b*1024 + j0 + 128 + ct*16 + l15];

    __syncthreads();    // publish h1c0

    // issue h1c1 (192..255) -> buf1
    #pragma unroll
    for (int p = 0; p < 8; ++p){
        int rr = (p*2 + ro) & 7;
        gld16(Vrow + (size_t)(192 + p*2)*256 + (size_t)((cs ^ rr) * 8),
              &sV[1][(w*16 + p*2) * 256]);
    }
    // compute h1c0 from buf0
    #pragma unroll
    for (int jt = 0; jt < 4; ++jt){
        bf16x8 bf[8];
        #pragma unroll
        for (int g = 0; g < 8; ++g)
            bf[g] = *(const bf16x8*)&sV[0][(jt*16 + l15)*256 + (((g*4 + lq) ^ s7) << 3)];
        #pragma unroll
        for (int g = 0; g < 8; ++g){
            acc[0][jt] = __builtin_amdgcn_mfma_f32_16x16x32_bf16(af[0][g], bf[g], acc[0][jt], 0, 0, 0);
            acc[1][jt] = __builtin_amdgcn_mfma_f32_16x16x32_bf16(af[1][g], bf[g], acc[1][jt], 0, 0, 0);
        }
    }

    __syncthreads();    // publish h1c1 (drain overlapped by h1c0 compute)

    // compute h1c1 from buf1
    #pragma unroll
    for (int jt = 0; jt < 4; ++jt){
        bf16x8 bf[8];
        #pragma unroll
        for (int g = 0; g < 8; ++g)
            bf[g] = *(const bf16x8*)&sV[1][(jt*16 + l15)*256 + (((g*4 + lq) ^ s7) << 3)];
        #pragma unroll
        for (int g = 0; g < 8; ++g){
            acc[0][4+jt] = __builtin_amdgcn_mfma_f32_16x16x32_bf16(af[0][g], bf[g], acc[0][4+jt], 0, 0, 0);
            acc[1][4+jt] = __builtin_amdgcn_mfma_f32_16x16x32_bf16(af[1][g], bf[g], acc[1][4+jt], 0, 0, 0);
        }
    }
    // epilogue-accumulate half1
    #pragma unroll
    for (int s = 0; s < 2; ++s){
        #pragma unroll
        for (int r = 0; r < 4; ++r){
            float a1 = 0.f;
            #pragma unroll
            for (int ct = 0; ct < 8; ++ct)
                a1 += __expf(fmaf(acc[s][ct][r], INVT, cbv1[ct]));
            ls[s][r] += a1;
        }
    }

    // reduce over the 16 lanes sharing each row; dense store via LDS bounce
    #pragma unroll
    for (int s = 0; s < 2; ++s){
        #pragma unroll
        for (int r = 0; r < 4; ++r){
            float v = ls[s][r];
            #pragma unroll
            for (int mm = 1; mm < 16; mm <<= 1)
                v += __shfl_xor(v, mm);
            ls[s][r] = v;
        }
    }
    if (l15 == 0){
        #pragma unroll
        for (int s = 0; s < 2; ++s)
            #pragma unroll
            for (int r = 0; r < 4; ++r)
                sRed[w][s*16 + lq*4 + r] = ls[s][r];
    }
    float* pp = psum + (((size_t)(b*4 + js)) << 10);
    if (lane < 32) pp[i0 + w*32 + lane] = sRed[w][lane];
}

// ---- banded positive max: one 16-lane group per row, <=5 candidate cols via idx.
__global__ __launch_bounds__(256) void pos_kernel(const short* __restrict__ E,
                                                  const short* __restrict__ V,
                                                  const int* __restrict__ mask,
                                                  const int* __restrict__ rank,
                                                  const int* __restrict__ idx,
                                                  const int* __restrict__ Tv,
                                                  float* __restrict__ pmax){
    int tid = threadIdx.x;
    int gl  = tid & 15;
    int rf  = (blockIdx.x * 256 + tid) >> 4;   // 0..32767
    int b   = rf >> 10;
    if (mask[rf] <= 0) return;

    int ri = rank[rf];
    int tv = Tv[b];
    int lo = ri - 2; if (lo < 0) lo = 0;
    int hi = ri + 2; if (hi > tv - 1) hi = tv - 1;

    const short* epp = E + (size_t)rf * 256 + gl * 16;
    float ev[16];
    {
        bf16x8 e0 = *(const bf16x8*)epp;
        bf16x8 e1 = *(const bf16x8*)(epp + 8);
        #pragma unroll
        for (int k = 0; k < 8; ++k){ ev[k] = bf2f(e0[k]); ev[8+k] = bf2f(e1[k]); }
    }
    float pm = -1e30f;
    for (int r = lo; r <= hi; ++r){
        int j = idx[b*1024 + r];
        const short* vpp = V + ((size_t)(b*1024) + j) * 256 + gl * 16;
        bf16x8 v0 = *(const bf16x8*)vpp;
        bf16x8 v1 = *(const bf16x8*)(vpp + 8);
        float s = 0.f;
        #pragma unroll
        for (int k = 0; k < 8; ++k){
            s = fmaf(ev[k],   bf2f(v0[k]), s);
            s = fmaf(ev[8+k], bf2f(v1[k]), s);
        }
        s += __shfl_xor(s, 1);
        s += __shfl_xor(s, 2);
        s += __shfl_xor(s, 4);
        s += __shfl_xor(s, 8);
        pm = fmaxf(pm, s);
    }
    if (gl == 0) pmax[rf] = pm * INVT;
}

// ---- partial reduce: 4 blocks per b, each thread one i; coalesced psum reads.
__global__ __launch_bounds__(256) void reduce_kernel(const float* __restrict__ psum,
                                                     const float* __restrict__ pmax,
                                                     const int* __restrict__ mask,
                                                     float* __restrict__ bsum){
    int b  = blockIdx.x >> 2;
    int i  = (blockIdx.x & 3) * 256 + threadIdx.x;
    int g  = b*1024 + i;
    float a = 0.f;
    if (mask[g] > 0){
        const float* pp = psum + ((size_t)b << 12);
        float ps = pp[i] + pp[i + 1024] + pp[i + 2048] + pp[i + 3072];
        a = logf(ps) - pmax[g];
    }
    #pragma unroll
    for (int m = 1; m < 64; m <<= 1) a += __shfl_xor(a, m);
    if ((threadIdx.x & 63) == 0 && a != 0.f) atomicAdd(&bsum[b], a);
}

// ---- final: out = sum_b (Tv>=2 ? bsum/Tv : 0) / 32
__global__ void final_kernel(const float* __restrict__ bsum,
                             const int* __restrict__ Tv,
                             float* __restrict__ out){
    int tid = threadIdx.x;
    float v = 0.f;
    if (tid < 32){
        int tv = Tv[tid];
        if (tv >= 2) v = bsum[tid] / (float)tv;
    }
    #pragma unroll
    for (int m = 1; m < 64; m <<= 1) v += __shfl_xor(v, m);
    if (tid == 0) out[0] = v / 32.0f;
}

extern "C" void kernel_launch(void* const* d_in, const int* in_sizes, int n_in,
                              void* d_out, int out_size, void* d_ws, size_t ws_size,
                              hipStream_t stream) {
    const float* eeg  = (const float*)d_in[0];
    const float* eye  = (const float*)d_in[1];
    const int*   mask = (const int*)d_in[2];
    const float* Weeg = (const float*)d_in[3];
    const float* Weye = (const float*)d_in[4];
    float* out = (float*)d_out;

    char* ws = (char*)d_ws;
    short* e_bf  = (short*)(ws);                       // 16 MiB
    short* v_bf  = (short*)(ws + 16777216);            // 16 MiB
    short* wbf   = (short*)(ws + 33554432);            // 256 KiB
    int*   rank  = (int*)  (ws + 33816576);            // 128 KiB
    int*   idx   = (int*)  (ws + 33947648);            // 128 KiB
    float* cb    = (float*)(ws + 34078720);            // 128 KiB
    float* psum  = (float*)(ws + 34209792);            // 512 KiB (32 b x 4 slices x 1024 i)
    float* pmax  = (float*)(ws + 34734080);            // 128 KiB
    int*   Tv    = (int*)  (ws + 34865152);            // 128 B
    float* bsum  = (float*)(ws + 34865280);            // 128 B

    prep_kernel<<<544, 256, 0, stream>>>(Weeg, Weye, mask, wbf, rank, idx, Tv, cb, bsum);
    proj_kernel<<<dim3(512, 2), 256, 0, stream>>>(eeg, eye, wbf, e_bf, v_bf);
    loss_kernel<<<1024, 256, 0, stream>>>(e_bf, v_bf, cb, psum);
    pos_kernel<<<2048, 256, 0, stream>>>(e_bf, v_bf, mask, rank, idx, Tv, pmax);
    reduce_kernel<<<128, 256, 0, stream>>>(psum, pmax, mask, bsum);
    final_kernel<<<1, 64, 0, stream>>>(bsum, Tv, out);
}